// Round 5
// baseline (301.322 us; speedup 1.0000x reference)
//
#include <hip/hip_runtime.h>

#define NUM_LAYERS 1000
#define DIM 10
#define STRIDE 112           // floats per affine slot (10x11 = 110, padded)
#define LPB 16               // layers per block
#define NBLK 63              // ceil(1000/16)

typedef float floatx4 __attribute__((ext_vector_type(4)));   // native vec for nontemporal

// Affine slot, col-major: slot[j*10 + r] = M[r][j] (j<10), slot[100+r] = c[r].
// compose: dst = G∘F : col_j(dst) = M_G * col_j(F) (+ c_G when j==10).
__device__ inline void compose_one(const float* __restrict__ src,
                                   float* __restrict__ dst,
                                   int c, int lane) {
    const float* F = src + (size_t)(2 * c) * STRIDE;
    const float* G = src + (size_t)(2 * c + 1) * STRIDE;
    float colf[DIM], o[DIM];
    #pragma unroll
    for (int r = 0; r < DIM; ++r) colf[r] = F[lane * DIM + r];
    #pragma unroll
    for (int r = 0; r < DIM; ++r) {
        float acc = (lane == DIM) ? G[100 + r] : 0.f;
        #pragma unroll
        for (int k = 0; k < DIM; ++k)
            acc += G[k * DIM + r] * colf[k];
        o[r] = acc;
    }
    float* D = dst + (size_t)c * STRIDE;
    #pragma unroll
    for (int r = 0; r < DIM; ++r) D[lane * DIM + r] = o[r];
}

// ---------------------------------------------------------------------------
// K1 (single dispatch): 63 blocks tree-compose 16 layers each; the LAST
// arriving block (atomicAdd on counter) folds all 63 chunk affines via a
// 6-level LDS tree and writes the final affine row-major to aff.
// Last-arrival pattern = no spinning = deadlock-free regardless of dispatch
// order or residency.  S regions: A = S[0..64 slots), B = S[64..96 slots).
// ---------------------------------------------------------------------------
__global__ __launch_bounds__(1024) void compose_all(const float* __restrict__ Ws,
                                                    const float* __restrict__ bs,
                                                    float* __restrict__ chunks,
                                                    float* __restrict__ aff,
                                                    unsigned int* __restrict__ counter) {
    __shared__ float S[96 * STRIDE];
    float* A = S;
    float* B = S + 64 * STRIDE;
    const int tid = threadIdx.x;
    const int blk = blockIdx.x;
    const int wave = tid >> 6, lane = tid & 63;

    // ---- phase 1: compose this block's 16 layers (identity-padded) ----
    for (int e = tid; e < LPB * 100; e += 1024) {
        int ll = e / 100, rem = e % 100;      // rem = r*10 + k
        int r = rem / 10, k = rem % 10;
        int l = blk * LPB + ll;
        float v = (l < NUM_LAYERS) ? Ws[(size_t)l * 100 + rem]
                                   : (r == k ? 1.f : 0.f);
        A[ll * STRIDE + k * DIM + r] = v;
    }
    for (int e = tid; e < LPB * DIM; e += 1024) {
        int ll = e / DIM, r = e % DIM;
        int l = blk * LPB + ll;
        A[ll * STRIDE + 100 + r] = (l < NUM_LAYERS) ? bs[(size_t)l * DIM + r] : 0.f;
    }
    {
        const float* src = A; float* dst = B;
        for (int n = LPB / 2; n >= 1; n >>= 1) {   // 8,4,2,1 -> ends in A slot 0
            __syncthreads();
            if (wave < n && lane <= DIM) compose_one(src, dst, wave, lane);
            float* t = dst; dst = (float*)src; src = t;
        }
    }
    __syncthreads();
    if (tid < 110) chunks[(size_t)blk * STRIDE + tid] = A[tid];

    // ---- phase 2: last block folds ----
    __threadfence();                                // release our chunk writes
    __shared__ unsigned int last;
    if (tid == 0)
        last = (atomicAdd(counter, 1u) == NBLK - 1) ? 1u : 0u;
    __syncthreads();
    if (!last) return;
    __threadfence();                                // acquire: invalidate stale lines

    for (int e = tid; e < 64 * STRIDE; e += 1024) {
        int c = e / STRIDE, pos = e % STRIDE;
        float v;
        if (pos >= 110)      v = 0.f;
        else if (c < NBLK)   v = chunks[(size_t)c * STRIDE + pos];
        else v = (pos < 100 && (pos / 10 == pos % 10)) ? 1.f : 0.f;  // identity
        A[e] = v;
    }
    {
        const float* src = A; float* dst = B;
        for (int n = 32; n >= 1; n >>= 1) {        // 32..1 -> ends in A slot 0
            __syncthreads();
            if (lane <= DIM)
                for (int c = wave; c < n; c += 16)
                    compose_one(src, dst, c, lane);
            float* t = dst; dst = (float*)src; src = t;
        }
    }
    __syncthreads();
    if (tid < 110) {
        if (tid < 100) {
            int j = tid / DIM, r = tid % DIM;      // A[j*10+r] = M[r][j]
            aff[r * DIM + j] = A[tid];
        } else {
            aff[tid] = A[tid];                     // bias
        }
    }
}

// ---------------------------------------------------------------------------
// K2: out = M x + c, 4 rows/thread = 10 x float4 each way. All 10 loads are
// issued before any compute (sched_barrier) for max memory-level parallelism;
// affine comes in via wave-uniform s_loads; stores are nontemporal (out is
// never re-read — keep L2/L3 for x). Clamped tail threads redo row nquads-1
// with identical values (benign).
// ---------------------------------------------------------------------------
__global__ __launch_bounds__(256) void apply_affine(const float* __restrict__ x,
                                                    const float* __restrict__ aff,
                                                    float* __restrict__ out,
                                                    int nquads) {
    int t = blockIdx.x * blockDim.x + threadIdx.x;
    if (t >= nquads) t = nquads - 1;

    const floatx4* xin = (const floatx4*)x + (size_t)t * 10;
    floatx4 v[10];
    #pragma unroll
    for (int i = 0; i < 10; ++i) v[i] = xin[i];

    // scalar affine loads (uniform, unconditional)
    float a[100], b[DIM];
    #pragma unroll
    for (int i = 0; i < 100; ++i) a[i] = aff[i];
    #pragma unroll
    for (int j = 0; j < DIM; ++j) b[j] = aff[100 + j];

    __builtin_amdgcn_sched_barrier(0);   // loads above, compute below

    const float* xv = (const float*)v;   // 40 floats, 4 rows
    float o[40];
    #pragma unroll
    for (int j = 0; j < DIM; ++j) {
        #pragma unroll
        for (int rr = 0; rr < 4; ++rr) {
            float acc = b[j];
            #pragma unroll
            for (int k = 0; k < DIM; ++k)
                acc += a[j * DIM + k] * xv[rr * DIM + k];
            o[rr * DIM + j] = acc;
        }
    }

    floatx4* op = (floatx4*)out + (size_t)t * 10;
    #pragma unroll
    for (int i = 0; i < 10; ++i) {
        floatx4 w = { o[4*i], o[4*i+1], o[4*i+2], o[4*i+3] };
        __builtin_nontemporal_store(w, op + i);
    }
}

extern "C" void kernel_launch(void* const* d_in, const int* in_sizes, int n_in,
                              void* d_out, int out_size, void* d_ws, size_t ws_size,
                              hipStream_t stream) {
    const float* x  = (const float*)d_in[0];   // [BATCH, 10]
    const float* Ws = (const float*)d_in[1];   // [1000, 10, 10]
    const float* bs = (const float*)d_in[2];   // [1000, 10]
    float* out = (float*)d_out;

    unsigned int* counter = (unsigned int*)d_ws;                  // 1 uint
    float* ws_aff    = (float*)d_ws + 32;                         // 110 floats
    float* ws_chunks = (float*)d_ws + 32 + 128;                   // NBLK*STRIDE floats

    const int batch  = in_sizes[0] / DIM;      // 2,000,000
    const int nquads = batch / 4;              // 500,000

    (void)hipMemsetAsync(counter, 0, sizeof(unsigned int), stream);
    compose_all<<<NBLK, 1024, 0, stream>>>(Ws, bs, ws_chunks, ws_aff, counter);

    const int threads = 256;
    const int blocks  = (nquads + threads - 1) / threads;
    apply_affine<<<blocks, threads, 0, stream>>>(x, ws_aff, out, nquads);
}

// Round 6
// 188.528 us; speedup vs baseline: 1.5983x; 1.5983x over previous
//
#include <hip/hip_runtime.h>

#define NUM_LAYERS 1000
#define DIM 10
#define STRIDE 112           // floats per affine slot (10x11 = 110, padded)
#define LPB 16               // layers per block
#define NBLK 63              // ceil(1000/16)

typedef float floatx4 __attribute__((ext_vector_type(4)));

// Affine slot, col-major: slot[j*10 + r] = M[r][j] (j<10), slot[100+r] = c[r].
// compose: dst = G∘F : col_j(dst) = M_G * col_j(F) (+ c_G when j==10).
__device__ inline void compose_one(const float* __restrict__ src,
                                   float* __restrict__ dst,
                                   int c, int lane) {
    const float* F = src + (size_t)(2 * c) * STRIDE;
    const float* G = src + (size_t)(2 * c + 1) * STRIDE;
    float colf[DIM], o[DIM];
    #pragma unroll
    for (int r = 0; r < DIM; ++r) colf[r] = F[lane * DIM + r];
    #pragma unroll
    for (int r = 0; r < DIM; ++r) {
        float acc = (lane == DIM) ? G[100 + r] : 0.f;
        #pragma unroll
        for (int k = 0; k < DIM; ++k)
            acc += G[k * DIM + r] * colf[k];
        o[r] = acc;
    }
    float* D = dst + (size_t)c * STRIDE;
    #pragma unroll
    for (int r = 0; r < DIM; ++r) D[lane * DIM + r] = o[r];
}

// ---------------------------------------------------------------------------
// K1 (single dispatch): 63 blocks tree-compose 16 layers each; the LAST
// arriving block (atomicAdd on counter) folds all 63 chunk affines via a
// 6-level LDS tree and writes the final affine row-major to aff.
// ---------------------------------------------------------------------------
__global__ __launch_bounds__(1024) void compose_all(const float* __restrict__ Ws,
                                                    const float* __restrict__ bs,
                                                    float* __restrict__ chunks,
                                                    float* __restrict__ aff,
                                                    unsigned int* __restrict__ counter) {
    __shared__ float S[96 * STRIDE];
    float* A = S;
    float* B = S + 64 * STRIDE;
    const int tid = threadIdx.x;
    const int blk = blockIdx.x;
    const int wave = tid >> 6, lane = tid & 63;

    // ---- phase 1: compose this block's 16 layers (identity-padded) ----
    for (int e = tid; e < LPB * 100; e += 1024) {
        int ll = e / 100, rem = e % 100;      // rem = r*10 + k
        int r = rem / 10, k = rem % 10;
        int l = blk * LPB + ll;
        float v = (l < NUM_LAYERS) ? Ws[(size_t)l * 100 + rem]
                                   : (r == k ? 1.f : 0.f);
        A[ll * STRIDE + k * DIM + r] = v;
    }
    for (int e = tid; e < LPB * DIM; e += 1024) {
        int ll = e / DIM, r = e % DIM;
        int l = blk * LPB + ll;
        A[ll * STRIDE + 100 + r] = (l < NUM_LAYERS) ? bs[(size_t)l * DIM + r] : 0.f;
    }
    {
        const float* src = A; float* dst = B;
        for (int n = LPB / 2; n >= 1; n >>= 1) {   // 8,4,2,1 -> ends in A slot 0
            __syncthreads();
            if (wave < n && lane <= DIM) compose_one(src, dst, wave, lane);
            float* t = dst; dst = (float*)src; src = t;
        }
    }
    __syncthreads();
    if (tid < 110) chunks[(size_t)blk * STRIDE + tid] = A[tid];

    // ---- phase 2: last block folds ----
    __threadfence();
    __shared__ unsigned int last;
    if (tid == 0)
        last = (atomicAdd(counter, 1u) == NBLK - 1) ? 1u : 0u;
    __syncthreads();
    if (!last) return;
    __threadfence();

    for (int e = tid; e < 64 * STRIDE; e += 1024) {
        int c = e / STRIDE, pos = e % STRIDE;
        float v;
        if (pos >= 110)      v = 0.f;
        else if (c < NBLK)   v = chunks[(size_t)c * STRIDE + pos];
        else v = (pos < 100 && (pos / 10 == pos % 10)) ? 1.f : 0.f;
        A[e] = v;
    }
    {
        const float* src = A; float* dst = B;
        for (int n = 32; n >= 1; n >>= 1) {        // 32..1 -> ends in A slot 0
            __syncthreads();
            if (lane <= DIM)
                for (int c = wave; c < n; c += 16)
                    compose_one(src, dst, c, lane);
            float* t = dst; dst = (float*)src; src = t;
        }
    }
    __syncthreads();
    if (tid < 110) {
        if (tid < 100) {
            int j = tid / DIM, r = tid % DIM;      // A[j*10+r] = M[r][j]
            aff[r * DIM + j] = A[tid];
        } else {
            aff[tid] = A[tid];                     // bias
        }
    }
}

// ---------------------------------------------------------------------------
// K2: out = M x + c, fully-coalesced version.
// Block = 256 threads, 2 rows/thread -> 512 rows = 1280 float4 per block.
// Phase 1: flat coalesced global->LDS (float4 stream, 4 KB/instr).
// Phase 2: thread reads its 2 rows (5 x ds_read_b128 at 7-quad stride:
//          28 floats ≡ 28 mod 32 -> each 8-lane group covers all 32 banks
//          exactly once -> conflict-free). Affine via wave-uniform s_loads.
// Phase 3: write results to OWN slots (no sync needed).
// Phase 4: flat coalesced LDS->global (cached stores; L2 merges lines).
// LDS = 256*7*16 = 28 KB -> 5 blocks/CU.
// ---------------------------------------------------------------------------
#define RPT 2                        // rows per thread
#define QPT 5                        // quads per thread (RPT*10/4)
#define QPAD 7                       // padded quads per thread (bank coverage)
#define BQUADS (256 * QPT)           // 1280 quads per block

__global__ __launch_bounds__(256) void apply_affine(const float* __restrict__ x,
                                                    const float* __restrict__ aff,
                                                    float* __restrict__ out,
                                                    long totQuads) {
    __shared__ floatx4 lds[256 * QPAD];
    const int tid = threadIdx.x;
    const long base = (long)blockIdx.x * BQUADS;

    // ---- phase 1: coalesced global -> LDS ----
    const floatx4* x4 = (const floatx4*)x;
    #pragma unroll
    for (int k = 0; k < QPT; ++k) {
        int i = k * 256 + tid;               // flat quad index within block
        long g = base + i;
        if (g < totQuads) {
            int t = i / QPT, q = i - t * QPT;
            lds[t * QPAD + q] = x4[g];
        }
    }
    __syncthreads();

    // ---- affine via uniform scalar loads (unconditional -> s_load) ----
    float a[100], b[DIM];
    #pragma unroll
    for (int i = 0; i < 100; ++i) a[i] = aff[i];
    #pragma unroll
    for (int j = 0; j < DIM; ++j) b[j] = aff[100 + j];

    // ---- phase 2: LDS -> reg (conflict-free b128), compute ----
    floatx4 v[QPT];
    #pragma unroll
    for (int q = 0; q < QPT; ++q) v[q] = lds[tid * QPAD + q];
    const float* xv = (const float*)v;       // 20 floats = 2 rows

    float o[RPT * DIM];
    #pragma unroll
    for (int j = 0; j < DIM; ++j) {
        #pragma unroll
        for (int rr = 0; rr < RPT; ++rr) {
            float acc = b[j];
            #pragma unroll
            for (int k = 0; k < DIM; ++k)
                acc += a[j * DIM + k] * xv[rr * DIM + k];
            o[rr * DIM + j] = acc;
        }
    }

    // ---- phase 3: results -> OWN LDS slots (no sync needed before) ----
    #pragma unroll
    for (int q = 0; q < QPT; ++q) {
        floatx4 w = { o[4*q], o[4*q+1], o[4*q+2], o[4*q+3] };
        lds[tid * QPAD + q] = w;
    }
    __syncthreads();

    // ---- phase 4: coalesced LDS -> global ----
    floatx4* o4 = (floatx4*)out;
    #pragma unroll
    for (int k = 0; k < QPT; ++k) {
        int i = k * 256 + tid;
        long g = base + i;
        if (g < totQuads) {
            int t = i / QPT, q = i - t * QPT;
            o4[g] = lds[t * QPAD + q];
        }
    }
}

extern "C" void kernel_launch(void* const* d_in, const int* in_sizes, int n_in,
                              void* d_out, int out_size, void* d_ws, size_t ws_size,
                              hipStream_t stream) {
    const float* x  = (const float*)d_in[0];   // [BATCH, 10]
    const float* Ws = (const float*)d_in[1];   // [1000, 10, 10]
    const float* bs = (const float*)d_in[2];   // [1000, 10]
    float* out = (float*)d_out;

    unsigned int* counter = (unsigned int*)d_ws;                  // 1 uint
    float* ws_aff    = (float*)d_ws + 32;                         // 110 floats
    float* ws_chunks = (float*)d_ws + 32 + 128;                   // NBLK*STRIDE floats

    const long batch    = in_sizes[0] / DIM;        // 2,000,000
    const long totQuads = batch * DIM / 4;          // 5,000,000 float4s

    (void)hipMemsetAsync(counter, 0, sizeof(unsigned int), stream);
    compose_all<<<NBLK, 1024, 0, stream>>>(Ws, bs, ws_chunks, ws_aff, counter);

    const int blocks = (int)((totQuads + BQUADS - 1) / BQUADS);   // 3907
    apply_affine<<<blocks, 256, 0, stream>>>(x, ws_aff, out, totQuads);
}

// Round 7
// 183.026 us; speedup vs baseline: 1.6463x; 1.0301x over previous
//
#include <hip/hip_runtime.h>

#define NUM_LAYERS 1000
#define DIM 10
#define STRIDE 112           // floats per affine slot (10x11 = 110, padded)
#define LPB 16               // layers per block
#define NBLK 63              // ceil(1000/16)

typedef float floatx4 __attribute__((ext_vector_type(4)));

// Affine slot, col-major: slot[j*10 + r] = M[r][j] (j<10), slot[100+r] = c[r].
// compose: dst = G∘F : col_j(dst) = M_G * col_j(F) (+ c_G when j==10).
__device__ inline void compose_one(const float* __restrict__ src,
                                   float* __restrict__ dst,
                                   int c, int lane) {
    const float* F = src + (size_t)(2 * c) * STRIDE;
    const float* G = src + (size_t)(2 * c + 1) * STRIDE;
    float colf[DIM], o[DIM];
    #pragma unroll
    for (int r = 0; r < DIM; ++r) colf[r] = F[lane * DIM + r];
    #pragma unroll
    for (int r = 0; r < DIM; ++r) {
        float acc = (lane == DIM) ? G[100 + r] : 0.f;
        #pragma unroll
        for (int k = 0; k < DIM; ++k)
            acc += G[k * DIM + r] * colf[k];
        o[r] = acc;
    }
    float* D = dst + (size_t)c * STRIDE;
    #pragma unroll
    for (int r = 0; r < DIM; ++r) D[lane * DIM + r] = o[r];
}

// ---------------------------------------------------------------------------
// K1 (single dispatch): 63 blocks tree-compose 16 layers each; the LAST
// arriving block (atomicAdd on counter) folds all 63 chunk affines via a
// 6-level LDS tree and writes the final affine row-major to aff.
// ---------------------------------------------------------------------------
__global__ __launch_bounds__(1024) void compose_all(const float* __restrict__ Ws,
                                                    const float* __restrict__ bs,
                                                    float* __restrict__ chunks,
                                                    float* __restrict__ aff,
                                                    unsigned int* __restrict__ counter) {
    __shared__ float S[96 * STRIDE];
    float* A = S;
    float* B = S + 64 * STRIDE;
    const int tid = threadIdx.x;
    const int blk = blockIdx.x;
    const int wave = tid >> 6, lane = tid & 63;

    // ---- phase 1: compose this block's 16 layers (identity-padded) ----
    for (int e = tid; e < LPB * 100; e += 1024) {
        int ll = e / 100, rem = e % 100;      // rem = r*10 + k
        int r = rem / 10, k = rem % 10;
        int l = blk * LPB + ll;
        float v = (l < NUM_LAYERS) ? Ws[(size_t)l * 100 + rem]
                                   : (r == k ? 1.f : 0.f);
        A[ll * STRIDE + k * DIM + r] = v;
    }
    for (int e = tid; e < LPB * DIM; e += 1024) {
        int ll = e / DIM, r = e % DIM;
        int l = blk * LPB + ll;
        A[ll * STRIDE + 100 + r] = (l < NUM_LAYERS) ? bs[(size_t)l * DIM + r] : 0.f;
    }
    {
        const float* src = A; float* dst = B;
        for (int n = LPB / 2; n >= 1; n >>= 1) {   // 8,4,2,1 -> ends in A slot 0
            __syncthreads();
            if (wave < n && lane <= DIM) compose_one(src, dst, wave, lane);
            float* t = dst; dst = (float*)src; src = t;
        }
    }
    __syncthreads();
    if (tid < 110) chunks[(size_t)blk * STRIDE + tid] = A[tid];

    // ---- phase 2: last block folds ----
    __threadfence();
    __shared__ unsigned int last;
    if (tid == 0)
        last = (atomicAdd(counter, 1u) == NBLK - 1) ? 1u : 0u;
    __syncthreads();
    if (!last) return;
    __threadfence();

    for (int e = tid; e < 64 * STRIDE; e += 1024) {
        int c = e / STRIDE, pos = e % STRIDE;
        float v;
        if (pos >= 110)      v = 0.f;
        else if (c < NBLK)   v = chunks[(size_t)c * STRIDE + pos];
        else v = (pos < 100 && (pos / 10 == pos % 10)) ? 1.f : 0.f;
        A[e] = v;
    }
    {
        const float* src = A; float* dst = B;
        for (int n = 32; n >= 1; n >>= 1) {        // 32..1 -> ends in A slot 0
            __syncthreads();
            if (lane <= DIM)
                for (int c = wave; c < n; c += 16)
                    compose_one(src, dst, c, lane);
            float* t = dst; dst = (float*)src; src = t;
        }
    }
    __syncthreads();
    if (tid < 110) {
        if (tid < 100) {
            int j = tid / DIM, r = tid % DIM;      // A[j*10+r] = M[r][j]
            aff[r * DIM + j] = A[tid];
        } else {
            aff[tid] = A[tid];                     // bias
        }
    }
}

// ---------------------------------------------------------------------------
// K2: out = M x + c, fully-coalesced, CONFLICT-FREE.
// QPAD=5 (no padding): slot map (i/5)*20 + (i%5)*4 == 4*i, so phase-1 writes
// and phase-4 reads are the IDENTITY layout -> flat lds[i] = x4[g] copies,
// consecutive lanes hit consecutive banks. Phase-2/3 per-thread stride is
// 20 words: lanes 0..7 cover all 32 banks exactly once (t*20 mod 32 =
// 0,20,8,28,16,4,24,12) -> conflict-free b128.
// Affine s_loads hoisted ABOVE phase 1 so scalar-load latency overlaps the
// global loads. Full blocks take an unguarded fast path (compiler batches
// all 5 loads -> single vmcnt wait); only the one partial block is guarded.
// LDS = 256*5*16 = 20 KB -> 8 blocks/CU (thread-limited), 100% theoretical occ.
// ---------------------------------------------------------------------------
#define RPT 2                        // rows per thread
#define QPT 5                        // quads per thread (RPT*10/4)
#define BQUADS (256 * QPT)           // 1280 quads per block

__global__ __launch_bounds__(256) void apply_affine(const float* __restrict__ x,
                                                    const float* __restrict__ aff,
                                                    float* __restrict__ out,
                                                    long totQuads) {
    __shared__ floatx4 lds[256 * QPT];
    const int tid = threadIdx.x;
    const long base = (long)blockIdx.x * BQUADS;
    const bool full = (base + BQUADS <= totQuads);

    // ---- affine via uniform scalar loads (unconditional -> s_load),
    //      issued first so lgkm latency overlaps the vector loads ----
    float a[100], b[DIM];
    #pragma unroll
    for (int i = 0; i < 100; ++i) a[i] = aff[i];
    #pragma unroll
    for (int j = 0; j < DIM; ++j) b[j] = aff[100 + j];

    // ---- phase 1: coalesced global -> LDS (identity layout) ----
    const floatx4* x4 = (const floatx4*)x;
    if (full) {
        #pragma unroll
        for (int k = 0; k < QPT; ++k) {
            int i = k * 256 + tid;
            lds[i] = x4[base + i];
        }
    } else {
        #pragma unroll
        for (int k = 0; k < QPT; ++k) {
            int i = k * 256 + tid;
            long g = base + i;
            if (g < totQuads) lds[i] = x4[g];
        }
    }
    __syncthreads();

    // ---- phase 2: LDS -> reg (stride-20, conflict-free b128), compute ----
    floatx4 v[QPT];
    #pragma unroll
    for (int q = 0; q < QPT; ++q) v[q] = lds[tid * QPT + q];
    const float* xv = (const float*)v;       // 20 floats = 2 rows

    float o[RPT * DIM];
    #pragma unroll
    for (int j = 0; j < DIM; ++j) {
        #pragma unroll
        for (int rr = 0; rr < RPT; ++rr) {
            float acc = b[j];
            #pragma unroll
            for (int k = 0; k < DIM; ++k)
                acc += a[j * DIM + k] * xv[rr * DIM + k];
            o[rr * DIM + j] = acc;
        }
    }

    // ---- phase 3: results -> OWN slots (no pre-sync needed) ----
    #pragma unroll
    for (int q = 0; q < QPT; ++q) {
        floatx4 w = { o[4*q], o[4*q+1], o[4*q+2], o[4*q+3] };
        lds[tid * QPT + q] = w;
    }
    __syncthreads();

    // ---- phase 4: coalesced LDS -> global (identity layout) ----
    floatx4* o4 = (floatx4*)out;
    if (full) {
        #pragma unroll
        for (int k = 0; k < QPT; ++k) {
            int i = k * 256 + tid;
            o4[base + i] = lds[i];
        }
    } else {
        #pragma unroll
        for (int k = 0; k < QPT; ++k) {
            int i = k * 256 + tid;
            long g = base + i;
            if (g < totQuads) o4[g] = lds[i];
        }
    }
}

extern "C" void kernel_launch(void* const* d_in, const int* in_sizes, int n_in,
                              void* d_out, int out_size, void* d_ws, size_t ws_size,
                              hipStream_t stream) {
    const float* x  = (const float*)d_in[0];   // [BATCH, 10]
    const float* Ws = (const float*)d_in[1];   // [1000, 10, 10]
    const float* bs = (const float*)d_in[2];   // [1000, 10]
    float* out = (float*)d_out;

    unsigned int* counter = (unsigned int*)d_ws;                  // 1 uint
    float* ws_aff    = (float*)d_ws + 32;                         // 110 floats
    float* ws_chunks = (float*)d_ws + 32 + 128;                   // NBLK*STRIDE floats

    const long batch    = in_sizes[0] / DIM;        // 2,000,000
    const long totQuads = batch * DIM / 4;          // 5,000,000 float4s

    (void)hipMemsetAsync(counter, 0, sizeof(unsigned int), stream);
    compose_all<<<NBLK, 1024, 0, stream>>>(Ws, bs, ws_chunks, ws_aff, counter);

    const int blocks = (int)((totQuads + BQUADS - 1) / BQUADS);   // 3907
    apply_affine<<<blocks, 256, 0, stream>>>(x, ws_aff, out, totQuads);
}